// Round 11
// baseline (178.243 us; speedup 1.0000x reference)
//
#include <hip/hip_runtime.h>
#include <hip/hip_bf16.h>
#include <stdint.h>

// Problem constants
#define B_   4
#define N_   2048
#define E_   1024
#define H_   16
#define DH_  64
#define M_   (B_*N_)    // 8192 tokens
#define KD_  1024       // GEMM K dim

typedef __bf16 bf16x8 __attribute__((ext_vector_type(8)));
typedef float  f32x4  __attribute__((ext_vector_type(4)));
typedef float  f32x16 __attribute__((ext_vector_type(16)));

__device__ __forceinline__ ushort f2bf(float f) {
  union { float f; uint32_t u; } x; x.f = f;
  uint32_t r = x.u + 0x7fffu + ((x.u >> 16) & 1u);
  return (ushort)(r >> 16);
}

__device__ __forceinline__ f32x4 mfma16(bf16x8 a, bf16x8 b, f32x4 c) {
  return __builtin_amdgcn_mfma_f32_16x16x32_bf16(a, b, c, 0, 0, 0);
}
__device__ __forceinline__ f32x16 mfma32(bf16x8 a, bf16x8 b, f32x16 c) {
  return __builtin_amdgcn_mfma_f32_32x32x16_bf16(a, b, c, 0, 0, 0);
}

__device__ __forceinline__ uint32_t cvtpk(float lo, float hi) {
  uint32_t d;
  asm("v_cvt_pk_bf16_f32 %0, %1, %2" : "=v"(d) : "v"(lo), "v"(hi));
  return d;
}

// 2^x as a single compiler-visible TRANS instruction (r5/r6 lesson: bare
// inline-asm v_exp_f32 skips the TRANS hazard wait -> corrupt values).
#if __has_builtin(__builtin_amdgcn_exp2f)
#define FEXP2(x) __builtin_amdgcn_exp2f(x)
#else
#define FEXP2(x) exp2f(x)
#endif

__device__ __forceinline__ void gload16(const void* g, void* l) {
  __builtin_amdgcn_global_load_lds(
      (const __attribute__((address_space(1))) uint32_t*)g,
      (__attribute__((address_space(3))) uint32_t*)l, 16, 0, 0);
}

// ---------------- fused prep: x->bf16, weights->bf16 (packed QKV), rope -----
__global__ void prep(const float* __restrict__ x,
                     const float* __restrict__ wq, const float* __restrict__ wk,
                     const float* __restrict__ wv, const float* __restrict__ wo,
                     ushort* __restrict__ xb, ushort* __restrict__ wqkv,
                     ushort* __restrict__ wob,
                     float* __restrict__ ct, float* __restrict__ st)
{
  int bid = blockIdx.x;
  if (bid < 8192) {                       // x: 8M f32 -> bf16
    int i = (bid * 256 + threadIdx.x) * 4;
    float4 v = *(const float4*)(x + i);
    ushort4 o; o.x = f2bf(v.x); o.y = f2bf(v.y); o.z = f2bf(v.z); o.w = f2bf(v.w);
    *(ushort4*)(xb + i) = o;
  } else if (bid < 12288) {               // weights: 4M f32 -> bf16
    int i = ((bid - 8192) * 256 + threadIdx.x) * 4;
    int which = i >> 20;
    int off = i & 1048575;
    const float* src = which == 0 ? wq : which == 1 ? wk : which == 2 ? wv : wo;
    float4 v = *(const float4*)(src + off);
    ushort4 o; o.x = f2bf(v.x); o.y = f2bf(v.y); o.z = f2bf(v.z); o.w = f2bf(v.w);
    if (which < 3) *(ushort4*)(wqkv + i) = o;
    else           *(ushort4*)(wob + off) = o;
  } else {                                // rope tables (2048 x 32)
    int idx = (bid - 12288) * 256 + threadIdx.x;
    int n = idx >> 5, i = idx & 31;
    double inv = exp(-(double)i * (9.210340371976184 / 32.0));
    float ang = (float)n * (float)inv;
    ct[idx] = cosf(ang);
    st[idx] = sinf(ang);
  }
}

// ============ 256x256 (BK=64) 4-phase deep-pipelined fused QKV GEMM ==========
// 512 threads = 8 waves (2M x 4N); per-wave C = 128 rows x 64 cols.
// Each wave reads ONE A-half (per wm) and ONE B-half (per wn). B-frags read
// once per K-tile (P1, held in regs); A-frags per-quadrant (P1..P4).
// Stage slots: P1: A.h0(T+1), P2: A.h1(T+1) -> other buffer (its A last read
// at P4(T-1)); P3: B.h0(T+2), P4: B.h1(T+2) -> current buffer (B read at P1).
// Leads: 3-6 phases. ONE counted wait per tile: vmcnt(4) at P1 (completes the
// A-halves of tile T; keeps the 2 newest B-halves of T+1 in flight). Raw
// s_barrier only (no vmcnt(0) drain). Queue depth bounded at 12 loads.
__launch_bounds__(512, 1)
__global__ void gemm_qkv8(const ushort* __restrict__ A, const ushort* __restrict__ W,
                          const float* __restrict__ bq, const float* __restrict__ bk,
                          const float* __restrict__ bv,
                          ushort* __restrict__ Qo, ushort* __restrict__ Ko,
                          ushort* __restrict__ Vto,
                          const float* __restrict__ cost, const float* __restrict__ sint)
{
  __shared__ char smem[131072];   // buf{0,1}: [A 32KB][B 32KB]
  const int tid = threadIdx.x;
  const int lane = tid & 63, w = tid >> 6;
  const int c = lane & 15, g = lane >> 4;
  const int wn = w & 3, wm = w >> 2;            // 2M x 4N wave grid
  // XCD-chunked bijective remap (384 % 8 == 0): xcd owns 4 consecutive
  // m-panels x all 12 n-panels -> 2MB of A L2-resident per XCD.
  const int sbid = (blockIdx.x & 7) * 48 + (blockIdx.x >> 3);
  const int m0 = (sbid / 12) * 256, n0 = (sbid % 12) * 256;

  // staging source (fixed per thread): dest flat F = j*8192 + tid*16
  // -> half-row = j*64 + (tid>>3), colbyte = (tid&7)*16 (XOR pre-swizzled)
  const int srow = tid >> 3;
  const int scbs = ((tid & 7) * 16) ^ ((srow & 7) << 4);
  const char* gA = (const char*)A + (size_t)(m0 + srow) * 2048 + scbs;
  const char* gB = (const char*)W + (size_t)(n0 + srow) * 2048 + scbs;

  f32x4 acc[8][4] = {};                         // [m-frag 0..7][n-frag 0..3]

#define STGA(HH, TT, DB) {                                                     \
    const char* s_ = gA + (size_t)(HH) * 262144 + (TT) * 128;                  \
    gload16(s_,          smem + (DB) + (HH) * 16384 + tid * 16);               \
    gload16(s_ + 131072, smem + (DB) + (HH) * 16384 + 8192 + tid * 16); }
#define STGB(HH, TT, DB) {                                                     \
    const char* s_ = gB + (size_t)(HH) * 262144 + (TT) * 128;                  \
    gload16(s_,          smem + (DB) + 32768 + (HH) * 16384 + tid * 16);       \
    gload16(s_ + 131072, smem + (DB) + 32768 + (HH) * 16384 + 8192 + tid * 16); }

#define RD_B()                                                                 \
    _Pragma("unroll") for (int n = 0; n < 4; ++n)                              \
    _Pragma("unroll") for (int kk = 0; kk < 2; ++kk) {                         \
      int row = wn * 64 + n * 16 + c;                                          \
      bfr[n][kk] = *(const bf16x8*)(smem + cur + 32768 + row * 128 +           \
                                    ((kk * 64 + g * 16) ^ ((row & 7) << 4)));  \
    }
#define RD_A(Q)                                                                \
    bf16x8 af[2][2];                                                           \
    _Pragma("unroll") for (int m = 0; m < 2; ++m)                              \
    _Pragma("unroll") for (int kk = 0; kk < 2; ++kk) {                         \
      int row = wm * 128 + (Q) * 32 + m * 16 + c;                              \
      af[m][kk] = *(const bf16x8*)(smem + cur + row * 128 +                    \
                                   ((kk * 64 + g * 16) ^ ((row & 7) << 4)));   \
    }
#define MM(Q)                                                                  \
    __builtin_amdgcn_s_setprio(1);                                             \
    _Pragma("unroll") for (int kk = 0; kk < 2; ++kk)                           \
    _Pragma("unroll") for (int m = 0; m < 2; ++m)                              \
    _Pragma("unroll") for (int n = 0; n < 4; ++n)                              \
      acc[(Q) * 2 + m][n] = mfma16(af[m][kk], bfr[n][kk], acc[(Q) * 2 + m][n]);\
    __builtin_amdgcn_s_setprio(0);

  // prologue: tile0 complete into buf0; tile1 B-halves into buf1
  STGA(0, 0, 0) STGA(1, 0, 0) STGB(0, 0, 0) STGB(1, 0, 0)
  STGB(0, 1, 65536) STGB(1, 1, 65536)

  bf16x8 bfr[4][2];
  for (int T = 0; T < 16; ++T) {
    const int cur = (T & 1) << 16, oth = cur ^ 65536;
    // ---- P1: await tile T's A (vmcnt(4) keeps 2 newest = B(T+1) halves) ----
    asm volatile("s_waitcnt vmcnt(4)" ::: "memory");
    __builtin_amdgcn_s_barrier();
    asm volatile("" ::: "memory");
    {
      RD_B(); RD_A(0)
      STGA(0, T + 1, oth)
      MM(0)
    }
    // ---- P2 ----
    __builtin_amdgcn_s_barrier();
    asm volatile("" ::: "memory");
    {
      RD_A(1)
      STGA(1, T + 1, oth)
      MM(1)
    }
    // ---- P3 ----
    __builtin_amdgcn_s_barrier();
    asm volatile("" ::: "memory");
    {
      RD_A(2)
      STGB(0, T + 2, cur)
      MM(2)
    }
    // ---- P4 ----
    __builtin_amdgcn_s_barrier();
    asm volatile("" ::: "memory");
    {
      RD_A(3)
      STGB(1, T + 2, cur)
      MM(3)
    }
  }
#undef STGA
#undef STGB
#undef RD_B
#undef RD_A
#undef MM

  // ---------------- epilogue (per-wave cols = exactly one 64-col head) ------
  const int sel = n0 >> 10;                     // 0=Q,1=K,2=V (256 | 1024)
  const int ncl = n0 & 1023;
  const int hcol = ncl + wn * 64;
  const int h = hcol >> 6;

  if (sel == 2) {                               // V, transposed store
#pragma unroll
    for (int mf = 0; mf < 8; ++mf) {
      int tok = m0 + wm * 128 + mf * 16 + 4 * g;
      int b = tok >> 11, nn = tok & 2047;
#pragma unroll
      for (int n = 0; n < 4; ++n) {
        int d = n * 16 + c;
        float bvv = bv[hcol + d];
        ushort4 o;
        o.x = f2bf(acc[mf][n][0] + bvv);
        o.y = f2bf(acc[mf][n][1] + bvv);
        o.z = f2bf(acc[mf][n][2] + bvv);
        o.w = f2bf(acc[mf][n][3] + bvv);
        *(ushort4*)(Vto + (((size_t)(b * 16 + h) * 64 + d) << 11) + nn) = o;
      }
    }
  } else {                                      // Q or K with RoPE
    const float* bias = sel ? bk : bq;
    ushort* outB = sel ? Ko : Qo;
    const float sc = sel ? 1.0f : 0.125f * 1.44269504088896340736f;
#pragma unroll
    for (int mf = 0; mf < 8; ++mf) {
#pragma unroll
      for (int r = 0; r < 4; ++r) {
        int tok = m0 + wm * 128 + mf * 16 + 4 * g + r;
        int b = tok >> 11, nn = tok & 2047;
        float v[4];
#pragma unroll
        for (int n = 0; n < 4; ++n)
          v[n] = acc[mf][n][r] + bias[hcol + n * 16 + c];
        ushort* orow = outB + ((size_t)(b * 16 + h) * 2048 + nn) * 64;
#pragma unroll
        for (int nf = 0; nf < 2; ++nf) {
          int d = nf * 16 + c;                  // d in [0,32)
          float cv = cost[nn * 32 + d];
          float sv = sint[nn * 32 + d];
          orow[d]      = f2bf((v[nf] * cv - v[nf + 2] * sv) * sc);
          orow[d + 32] = f2bf((v[nf + 2] * cv + v[nf] * sv) * sc);
        }
      }
    }
  }
}

// ======== shared 128x128 bf16 K-loop (BK=64, gload_lds + XOR swizzle) ========
#define GEMM_KLOOP(Aptr, Wptr)                                                 \
  for (int k0 = 0; k0 < KD_; k0 += 64) {                                       \
    _Pragma("unroll")                                                          \
    for (int i = 0; i < 4; ++i) {                                              \
      uint32_t flat = i * 4096 + w * 1024 + lane * 16;                         \
      uint32_t row = flat >> 7, cb = flat & 127;                               \
      uint32_t cbs = cb ^ ((row & 7) << 4);                                    \
      gload16((const char*)(Aptr) + (size_t)(m0 + row) * 2048 + k0 * 2 + cbs,  \
              smA + i * 4096 + w * 1024);                                      \
      gload16((const char*)(Wptr) + (size_t)(n0 + row) * 2048 + k0 * 2 + cbs,  \
              smB + i * 4096 + w * 1024);                                      \
    }                                                                          \
    __syncthreads();                                                           \
    bf16x8 af[4][2], bfr[4][2];                                                \
    _Pragma("unroll")                                                          \
    for (int mf = 0; mf < 4; ++mf)                                             \
      _Pragma("unroll")                                                        \
      for (int kk = 0; kk < 2; ++kk) {                                         \
        int row = wr * 64 + mf * 16 + c;                                       \
        int cb = (kk * 64 + g * 16) ^ ((row & 7) << 4);                        \
        af[mf][kk] = *(const bf16x8*)(smA + row * 128 + cb);                   \
        int rowb = wc * 64 + mf * 16 + c;                                      \
        int cbb = (kk * 64 + g * 16) ^ ((rowb & 7) << 4);                      \
        bfr[mf][kk] = *(const bf16x8*)(smB + rowb * 128 + cbb);                \
      }                                                                        \
    _Pragma("unroll")                                                          \
    for (int kk = 0; kk < 2; ++kk)                                             \
      _Pragma("unroll")                                                        \
      for (int mf = 0; mf < 4; ++mf)                                           \
        _Pragma("unroll")                                                      \
        for (int nf = 0; nf < 4; ++nf)                                         \
          acc[mf][nf] = mfma16(af[mf][kk], bfr[nf][kk], acc[mf][nf]);          \
    __syncthreads();                                                           \
  }

// ---------------- output GEMM: out = attn @ wo^T + bo (f32) ----------------
__launch_bounds__(256, 3)
__global__ void gemm_out(const ushort* __restrict__ A, const ushort* __restrict__ W,
                         const float* __restrict__ bias, float* __restrict__ outF)
{
  __shared__ char smem[32768];
  char* smA = smem;
  char* smB = smem + 16384;
  const int tid = threadIdx.x;
  const int lane = tid & 63, w = tid >> 6;
  const int c = lane & 15, g = lane >> 4;
  const int m0 = blockIdx.x * 128, n0 = blockIdx.y * 128;
  const int wr = w >> 1, wc = w & 1;

  f32x4 acc[4][4] = {};
  GEMM_KLOOP(A, W)

  const int colbase = n0 + wc * 64;
#pragma unroll
  for (int mf = 0; mf < 4; ++mf) {
    int rowb = m0 + wr * 64 + mf * 16 + 4 * g;
#pragma unroll
    for (int nf = 0; nf < 4; ++nf) {
      int f = colbase + nf * 16 + c;
      float bvv = bias[f];
#pragma unroll
      for (int r = 0; r < 4; ++r)
        outF[(size_t)(rowb + r) * 1024 + f] = acc[mf][nf][r] + bvv;
    }
  }
}

// ---------------- flash attention (r7 config: 8 waves, grid 512) -------------
// Q,K: (B,H,N,64) bf16 (Q pre-scaled by 0.125*log2e); Vt: (B,H,64,N) bf16
// O: (B,N,E) bf16.  Block: 8 waves x 32 q = 256 q rows. KV tile 64, dbuf LDS.
// XCD remap: all 8 q-blocks of a head land on one XCD (K/V L2-resident).
__launch_bounds__(512, 4)
__global__ void flash_k(const ushort* __restrict__ Q, const ushort* __restrict__ K,
                        const ushort* __restrict__ Vt, const uint8_t* __restrict__ mask,
                        ushort* __restrict__ O)
{
  __shared__ char smem[36864];   // 2 x (K 8KB + V 8KB) dbuf; epilogue uses 36KB
  const int tid = threadIdx.x;
  const int lane = tid & 63, w = tid >> 6;
  const int l31 = lane & 31, hi = lane >> 5;
  const int L = blockIdx.x;            // 0..511
  const int xcd = L & 7, slot = L >> 3;
  const int cc = slot >> 3, qb = slot & 7;
  const int b = cc >> 1, h = xcd + 8 * (cc & 1);
  const int q0 = qb * 256;
  const size_t head = (size_t)(b * 16 + h) * (2048 * 64);
  const ushort* Qh = Q + head;
  const uint8_t* mb = mask + b * 2048;

  const int qrow = q0 + w * 32 + l31;
  bf16x8 qf[4];
#pragma unroll
  for (int kk = 0; kk < 4; ++kk)
    qf[kk] = *(const bf16x8*)(Qh + (size_t)qrow * 64 + kk * 16 + hi * 8);

  uint64_t mm;
  {
    const uint64_t* m64 = (const uint64_t*)mb;
    mm = m64[lane * 4 + 0] | m64[lane * 4 + 1] | m64[lane * 4 + 2] | m64[lane * 4 + 3];
  }
  const bool anymask = __any(mm != 0);

  bf16x8 vones;
#pragma unroll
  for (int j = 0; j < 8; ++j) vones[j] = (__bf16)1.0f;

  f32x16 Oa0 = {}, Oa1 = {}, Sacc = {};

  const int srow = tid >> 3;                 // 0..63
  const int scb = (tid & 7) * 16;
  const int cbs = scb ^ ((srow & 7) << 4);
  const char* Kg = (const char*)(K + head) + srow * 128 + cbs;
  const char* Vg = (const char*)(Vt + head) + srow * 4096 + cbs;

  gload16(Kg, smem + w * 1024);
  gload16(Vg, smem + 8192 + w * 1024);
  Kg += 8192;
  Vg += 128;
  __syncthreads();

  const int swz = (l31 & 7) << 4;

#define FLASH_TILE(T, CBUF, SBUF, DO_STAGE)                                    \
  {                                                                            \
    if (DO_STAGE) {                                                            \
      gload16(Kg, smem + (SBUF) + w * 1024);                                   \
      gload16(Vg, smem + (SBUF) + 8192 + w * 1024);                            \
      Kg += 8192; Vg += 128;                                                   \
    }                                                                          \
    const char* bK = smem + (CBUF);                                            \
    const char* bV = smem + (CBUF) + 8192;                                     \
    f32x16 s0 = {}, s1 = {};                                                   \
    __builtin_amdgcn_s_setprio(1);                                             \
    _Pragma("unroll")                                                          \
    for (int kk = 0; kk < 4; ++kk) {                                           \
      int col = (32 * kk + 16 * hi) ^ swz;                                     \
      bf16x8 k0 = *(const bf16x8*)(bK + l31 * 128 + col);                      \
      bf16x8 k1 = *(const bf16x8*)(bK + (l31 + 32) * 128 + col);               \
      s0 = mfma32(k0, qf[kk], s0);                                             \
      s1 = mfma32(k1, qf[kk], s1);                                             \
    }                                                                          \
    __builtin_amdgcn_s_setprio(0);                                             \
    float p0[16], p1[16];                                                      \
    _Pragma("unroll")                                                          \
    for (int i = 0; i < 16; ++i) {                                             \
      p0[i] = FEXP2(s0[i]);                                                    \
      p1[i] = FEXP2(s1[i]);                                                    \
    }                                                                          \
    if (anymask) {                                                             \
      int kv0 = (T) * 64;                                                      \
      _Pragma("unroll")                                                        \
      for (int r = 0; r < 16; ++r) {                                           \
        int crow = (r & 3) + 8 * (r >> 2) + 4 * hi;                            \
        if (mb[kv0 + crow]) p0[r] = 0.f;                                       \
        if (mb[kv0 + 32 + crow]) p1[r] = 0.f;                                  \
      }                                                                        \
    }                                                                          \
    uint32_t pw[4][4];                                                         \
    _Pragma("unroll")                                                          \
    for (int half = 0; half < 2; ++half) {                                     \
      const float* p = half ? p1 : p0;                                         \
      uint32_t alo0 = cvtpk(p[0], p[1]),  ahi0 = cvtpk(p[2], p[3]);            \
      uint32_t alo1 = cvtpk(p[4], p[5]),  ahi1 = cvtpk(p[6], p[7]);            \
      uint32_t alo2 = cvtpk(p[8], p[9]),  ahi2 = cvtpk(p[10], p[11]);          \
      uint32_t alo3 = cvtpk(p[12], p[13]), ahi3 = cvtpk(p[14], p[15]);         \
      auto r0 = __builtin_amdgcn_permlane32_swap(alo0, alo1, false, false);    \
      auto r1 = __builtin_amdgcn_permlane32_swap(ahi0, ahi1, false, false);    \
      auto r2 = __builtin_amdgcn_permlane32_swap(alo2, alo3, false, false);    \
      auto r3 = __builtin_amdgcn_permlane32_swap(ahi2, ahi3, false, false);    \
      pw[half * 2 + 0][0] = r0[0]; pw[half * 2 + 0][2] = r0[1];                \
      pw[half * 2 + 0][1] = r1[0]; pw[half * 2 + 0][3] = r1[1];                \
      pw[half * 2 + 1][0] = r2[0]; pw[half * 2 + 1][2] = r2[1];                \
      pw[half * 2 + 1][1] = r3[0]; pw[half * 2 + 1][3] = r3[1];                \
    }                                                                          \
    __builtin_amdgcn_s_setprio(1);                                             \
    _Pragma("unroll")                                                          \
    for (int c4 = 0; c4 < 4; ++c4) {                                           \
      union { uint32_t u[4]; bf16x8 v; } pf;                                   \
      pf.u[0] = pw[c4][0]; pf.u[1] = pw[c4][1];                                \
      pf.u[2] = pw[c4][2]; pf.u[3] = pw[c4][3];                                \
      int col = (32 * c4 + 16 * hi) ^ swz;                                     \
      bf16x8 v0 = *(const bf16x8*)(bV + l31 * 128 + col);                      \
      bf16x8 v1 = *(const bf16x8*)(bV + (l31 + 32) * 128 + col);               \
      Oa0 = mfma32(v0, pf.v, Oa0);                                             \
      Oa1 = mfma32(v1, pf.v, Oa1);                                             \
      Sacc = mfma32(vones, pf.v, Sacc);                                        \
    }                                                                          \
    __builtin_amdgcn_s_setprio(0);                                             \
    __syncthreads();                                                           \
  }

  for (int t = 0; t < N_ / 64; t += 2) {
    FLASH_TILE(t,     0,     16384, true)
    FLASH_TILE(t + 1, 16384, 0,     (t + 2 < N_ / 64))
  }
#undef FLASH_TILE

  float inv = 1.0f / Sacc[0];
  char* tr = smem + w * 4608;
#pragma unroll
  for (int db = 0; db < 2; ++db) {
    const f32x16& o = db ? Oa1 : Oa0;
#pragma unroll
    for (int a = 0; a < 4; ++a) {
      uint32_t lo = cvtpk(o[4 * a] * inv, o[4 * a + 1] * inv);
      uint32_t hi2 = cvtpk(o[4 * a + 2] * inv, o[4 * a + 3] * inv);
      *(uint2*)(tr + l31 * 144 + db * 64 + a * 16 + hi * 8) = make_uint2(lo, hi2);
    }
  }
  __asm__ volatile("" ::: "memory");
#pragma unroll
  for (int it = 0; it < 4; ++it) {
    uint4 v = *(const uint4*)(tr + l31 * 144 + it * 32 + hi * 16);
    int n = q0 + w * 32 + l31;
    *(uint4*)(O + (size_t)(b * 2048 + n) * 1024 + h * 64 + it * 16 + hi * 8) = v;
  }
}

// ---------------- host ----------------
extern "C" void kernel_launch(void* const* d_in, const int* in_sizes, int n_in,
                              void* d_out, int out_size, void* d_ws, size_t ws_size,
                              hipStream_t stream)
{
  (void)in_sizes; (void)n_in; (void)out_size; (void)ws_size;
  const float* x  = (const float*)d_in[0];
  const float* wq = (const float*)d_in[1];
  const float* bq = (const float*)d_in[2];
  const float* wk = (const float*)d_in[3];
  const float* bk = (const float*)d_in[4];
  const float* wv = (const float*)d_in[5];
  const float* bv = (const float*)d_in[6];
  const float* wo = (const float*)d_in[7];
  const float* bo = (const float*)d_in[8];
  const uint8_t* mask = (const uint8_t*)d_in[9];
  float* out = (float*)d_out;

  char* ws = (char*)d_ws;
  ushort* xb    = (ushort*)(ws + 0);              // 16 MB  (also attn-out bf16)
  ushort* Ab    = xb;
  ushort* wqkvb = (ushort*)(ws + 16777216);       // 6 MB packed [wq;wk;wv]
  ushort* wob   = (ushort*)(ws + 23068672);       // 2 MB
  ushort* Qb    = (ushort*)(ws + 25165824);       // 16 MB (B,H,N,Dh)
  ushort* Kb    = (ushort*)(ws + 41943040);       // 16 MB
  ushort* Vtb   = (ushort*)(ws + 58720256);       // 16 MB (B,H,Dh,N)
  float*  cost  = (float*)(ws + 75497472);        // 256 KB
  float*  sint  = (float*)(ws + 75759616);        // 256 KB

  prep<<<12544, 256, 0, stream>>>(x, wq, wk, wv, wo, xb, wqkvb, wob, cost, sint);

  gemm_qkv8<<<384, 512, 0, stream>>>(xb, wqkvb, bq, bk, bv,
                                     Qb, Kb, Vtb, cost, sint);

  flash_k<<<512, 512, 0, stream>>>(Qb, Kb, Vtb, mask, Ab);

  gemm_out<<<dim3(M_ / 128, 8), 256, 0, stream>>>(Ab, wob, bo, out);
}

// Round 12
// 166.996 us; speedup vs baseline: 1.0674x; 1.0674x over previous
//
#include <hip/hip_runtime.h>
#include <hip/hip_bf16.h>
#include <stdint.h>

// Problem constants
#define B_   4
#define N_   2048
#define E_   1024
#define H_   16
#define DH_  64
#define M_   (B_*N_)    // 8192 tokens
#define KD_  1024       // GEMM K dim

typedef __bf16 bf16x8 __attribute__((ext_vector_type(8)));
typedef float  f32x4  __attribute__((ext_vector_type(4)));
typedef float  f32x16 __attribute__((ext_vector_type(16)));

__device__ __forceinline__ ushort f2bf(float f) {
  union { float f; uint32_t u; } x; x.f = f;
  uint32_t r = x.u + 0x7fffu + ((x.u >> 16) & 1u);
  return (ushort)(r >> 16);
}

__device__ __forceinline__ f32x4 mfma16(bf16x8 a, bf16x8 b, f32x4 c) {
  return __builtin_amdgcn_mfma_f32_16x16x32_bf16(a, b, c, 0, 0, 0);
}
__device__ __forceinline__ f32x16 mfma32(bf16x8 a, bf16x8 b, f32x16 c) {
  return __builtin_amdgcn_mfma_f32_32x32x16_bf16(a, b, c, 0, 0, 0);
}

__device__ __forceinline__ uint32_t cvtpk(float lo, float hi) {
  uint32_t d;
  asm("v_cvt_pk_bf16_f32 %0, %1, %2" : "=v"(d) : "v"(lo), "v"(hi));
  return d;
}

// 2^x as a single compiler-visible TRANS instruction (r5/r6 lesson: bare
// inline-asm v_exp_f32 skips the TRANS hazard wait -> corrupt values).
#if __has_builtin(__builtin_amdgcn_exp2f)
#define FEXP2(x) __builtin_amdgcn_exp2f(x)
#else
#define FEXP2(x) exp2f(x)
#endif

__device__ __forceinline__ void gload16(const void* g, void* l) {
  __builtin_amdgcn_global_load_lds(
      (const __attribute__((address_space(1))) uint32_t*)g,
      (__attribute__((address_space(3))) uint32_t*)l, 16, 0, 0);
}

// ---------------- fused prep: x->bf16, weights->bf16 (packed QKV), rope -----
__global__ void prep(const float* __restrict__ x,
                     const float* __restrict__ wq, const float* __restrict__ wk,
                     const float* __restrict__ wv, const float* __restrict__ wo,
                     ushort* __restrict__ xb, ushort* __restrict__ wqkv,
                     ushort* __restrict__ wob,
                     float* __restrict__ ct, float* __restrict__ st)
{
  int bid = blockIdx.x;
  if (bid < 8192) {                       // x: 8M f32 -> bf16
    int i = (bid * 256 + threadIdx.x) * 4;
    float4 v = *(const float4*)(x + i);
    ushort4 o; o.x = f2bf(v.x); o.y = f2bf(v.y); o.z = f2bf(v.z); o.w = f2bf(v.w);
    *(ushort4*)(xb + i) = o;
  } else if (bid < 12288) {               // weights: 4M f32 -> bf16
    int i = ((bid - 8192) * 256 + threadIdx.x) * 4;
    int which = i >> 20;
    int off = i & 1048575;
    const float* src = which == 0 ? wq : which == 1 ? wk : which == 2 ? wv : wo;
    float4 v = *(const float4*)(src + off);
    ushort4 o; o.x = f2bf(v.x); o.y = f2bf(v.y); o.z = f2bf(v.z); o.w = f2bf(v.w);
    if (which < 3) *(ushort4*)(wqkv + i) = o;
    else           *(ushort4*)(wob + off) = o;
  } else {                                // rope tables (2048 x 32)
    int idx = (bid - 12288) * 256 + threadIdx.x;
    int n = idx >> 5, i = idx & 31;
    double inv = exp(-(double)i * (9.210340371976184 / 32.0));
    float ang = (float)n * (float)inv;
    ct[idx] = cosf(ang);
    st[idx] = sinf(ang);
  }
}

// ======== shared 128x128 bf16 K-loop (BK=64, gload_lds + XOR swizzle) ========
#define GEMM_KLOOP(Aptr, Wptr)                                                 \
  for (int k0 = 0; k0 < KD_; k0 += 64) {                                       \
    _Pragma("unroll")                                                          \
    for (int i = 0; i < 4; ++i) {                                              \
      uint32_t flat = i * 4096 + w * 1024 + lane * 16;                         \
      uint32_t row = flat >> 7, cb = flat & 127;                               \
      uint32_t cbs = cb ^ ((row & 7) << 4);                                    \
      gload16((const char*)(Aptr) + (size_t)(m0 + row) * 2048 + k0 * 2 + cbs,  \
              smA + i * 4096 + w * 1024);                                      \
      gload16((const char*)(Wptr) + (size_t)(n0 + row) * 2048 + k0 * 2 + cbs,  \
              smB + i * 4096 + w * 1024);                                      \
    }                                                                          \
    __syncthreads();                                                           \
    bf16x8 af[4][2], bfr[4][2];                                                \
    _Pragma("unroll")                                                          \
    for (int mf = 0; mf < 4; ++mf)                                             \
      _Pragma("unroll")                                                        \
      for (int kk = 0; kk < 2; ++kk) {                                         \
        int row = wr * 64 + mf * 16 + c;                                       \
        int cb = (kk * 64 + g * 16) ^ ((row & 7) << 4);                        \
        af[mf][kk] = *(const bf16x8*)(smA + row * 128 + cb);                   \
        int rowb = wc * 64 + mf * 16 + c;                                      \
        int cbb = (kk * 64 + g * 16) ^ ((rowb & 7) << 4);                      \
        bfr[mf][kk] = *(const bf16x8*)(smB + rowb * 128 + cbb);                \
      }                                                                        \
    _Pragma("unroll")                                                          \
    for (int kk = 0; kk < 2; ++kk)                                             \
      _Pragma("unroll")                                                        \
      for (int mf = 0; mf < 4; ++mf)                                           \
        _Pragma("unroll")                                                      \
        for (int nf = 0; nf < 4; ++nf)                                         \
          acc[mf][nf] = mfma16(af[mf][kk], bfr[nf][kk], acc[mf][nf]);          \
    __syncthreads();                                                           \
  }

// ---------------- fused QKV GEMM: Y = x @ Wqkv^T + b, per-block epilogue -----
// W packed [3072][1024]: rows 0-1023 wq, 1024-2047 wk, 2048-3071 wv.
__launch_bounds__(256, 3)
__global__ void gemm_qkv(const ushort* __restrict__ A, const ushort* __restrict__ W,
                         const float* __restrict__ bq, const float* __restrict__ bk,
                         const float* __restrict__ bv,
                         ushort* __restrict__ Qo, ushort* __restrict__ Ko,
                         ushort* __restrict__ Vto,
                         const float* __restrict__ cost, const float* __restrict__ sint)
{
  __shared__ char smem[32768];
  char* smA = smem;
  char* smB = smem + 16384;
  const int tid = threadIdx.x;
  const int lane = tid & 63, w = tid >> 6;
  const int c = lane & 15, g = lane >> 4;
  const int m0 = blockIdx.x * 128, n0 = blockIdx.y * 128;
  const int wr = w >> 1, wc = w & 1;

  f32x4 acc[4][4] = {};
  GEMM_KLOOP(A, W)

  const int sel = n0 >> 10;               // block-uniform: 0=Q,1=K,2=V
  const int ncol = n0 & 1023;
  const int colbase = ncol + wc * 64;
  const int h = colbase >> 6;

  if (sel == 2) {                         // V, transposed store
#pragma unroll
    for (int mf = 0; mf < 4; ++mf) {
      int tok = m0 + wr * 64 + mf * 16 + 4 * g;
      int b = tok >> 11, n = tok & 2047;
#pragma unroll
      for (int nf = 0; nf < 4; ++nf) {
        int d = nf * 16 + c;
        float bvv = bv[colbase + nf * 16 + c];
        ushort4 o;
        o.x = f2bf(acc[mf][nf][0] + bvv);
        o.y = f2bf(acc[mf][nf][1] + bvv);
        o.z = f2bf(acc[mf][nf][2] + bvv);
        o.w = f2bf(acc[mf][nf][3] + bvv);
        *(ushort4*)(Vto + (((size_t)(b * 16 + h) * 64 + d) << 11) + n) = o;
      }
    }
  } else {                                // Q or K with RoPE
    const float* bias = sel ? bk : bq;
    ushort* outB = sel ? Ko : Qo;
    const float sc = sel ? 1.0f : 0.125f * 1.44269504088896340736f;
#pragma unroll
    for (int mf = 0; mf < 4; ++mf) {
#pragma unroll
      for (int r = 0; r < 4; ++r) {
        int tok = m0 + wr * 64 + mf * 16 + 4 * g + r;
        int b = tok >> 11, n = tok & 2047;
        float v[4];
#pragma unroll
        for (int nf = 0; nf < 4; ++nf)
          v[nf] = acc[mf][nf][r] + bias[colbase + nf * 16 + c];
        ushort* orow = outB + ((size_t)(b * 16 + h) * 2048 + n) * 64;
#pragma unroll
        for (int nf = 0; nf < 2; ++nf) {
          int d = nf * 16 + c;                 // d in [0,32)
          float cv = cost[n * 32 + d];
          float sv = sint[n * 32 + d];
          orow[d]      = f2bf((v[nf] * cv - v[nf + 2] * sv) * sc);
          orow[d + 32] = f2bf((v[nf + 2] * cv + v[nf] * sv) * sc);
        }
      }
    }
  }
}

// ---------------- output GEMM: out = attn @ wo^T + bo (f32) ----------------
__launch_bounds__(256, 3)
__global__ void gemm_out(const ushort* __restrict__ A, const ushort* __restrict__ W,
                         const float* __restrict__ bias, float* __restrict__ outF)
{
  __shared__ char smem[32768];
  char* smA = smem;
  char* smB = smem + 16384;
  const int tid = threadIdx.x;
  const int lane = tid & 63, w = tid >> 6;
  const int c = lane & 15, g = lane >> 4;
  const int m0 = blockIdx.x * 128, n0 = blockIdx.y * 128;
  const int wr = w >> 1, wc = w & 1;

  f32x4 acc[4][4] = {};
  GEMM_KLOOP(A, W)

  const int colbase = n0 + wc * 64;
#pragma unroll
  for (int mf = 0; mf < 4; ++mf) {
    int rowb = m0 + wr * 64 + mf * 16 + 4 * g;
#pragma unroll
    for (int nf = 0; nf < 4; ++nf) {
      int f = colbase + nf * 16 + c;
      float bvv = bias[f];
#pragma unroll
      for (int r = 0; r < 4; ++r)
        outF[(size_t)(rowb + r) * 1024 + f] = acc[mf][nf][r] + bvv;
    }
  }
}

// ---------------- flash attention, swapped-QK^T 32x32, max-free softmax ------
// Q,K: (B,H,N,64) bf16 (Q pre-scaled by 0.125*log2e); Vt: (B,H,64,N) bf16
// O: (B,N,E) bf16.  Block: 8 waves x 32 q = 256 q rows. KV tile 64, dbuf LDS.
// 1D grid of 512, XCD-aware remap: all 8 q-blocks of a head land on one XCD
// (xcd = h&7), so each XCD's L2 holds its heads' K/V (~3MB < 4MB).
__launch_bounds__(512, 4)
__global__ void flash_k(const ushort* __restrict__ Q, const ushort* __restrict__ K,
                        const ushort* __restrict__ Vt, const uint8_t* __restrict__ mask,
                        ushort* __restrict__ O)
{
  __shared__ char smem[36864];   // 2 x (K 8KB + V 8KB) dbuf; epilogue uses 36KB
  const int tid = threadIdx.x;
  const int lane = tid & 63, w = tid >> 6;
  const int l31 = lane & 31, hi = lane >> 5;
  // XCD-aware block remap (bijective): L -> (q-block, head, batch)
  const int L = blockIdx.x;            // 0..511
  const int xcd = L & 7, slot = L >> 3;
  const int cc = slot >> 3, qb = slot & 7;
  const int b = cc >> 1, h = xcd + 8 * (cc & 1);
  const int q0 = qb * 256;
  const size_t head = (size_t)(b * 16 + h) * (2048 * 64);
  const ushort* Qh = Q + head;
  const uint8_t* mb = mask + b * 2048;

  // Q fragments (B-operand of swapped QK^T): lane (q=l31,hi) holds Q[q][kk*16+hi*8+j]
  const int qrow = q0 + w * 32 + l31;
  bf16x8 qf[4];
#pragma unroll
  for (int kk = 0; kk < 4; ++kk)
    qf[kk] = *(const bf16x8*)(Qh + (size_t)qrow * 64 + kk * 16 + hi * 8);

  // one-shot mask scan; hot path (all-false) does zero mask work
  uint64_t mm;
  {
    const uint64_t* m64 = (const uint64_t*)mb;
    mm = m64[lane * 4 + 0] | m64[lane * 4 + 1] | m64[lane * 4 + 2] | m64[lane * 4 + 3];
  }
  const bool anymask = __any(mm != 0);

  bf16x8 vones;
#pragma unroll
  for (int j = 0; j < 8; ++j) vones[j] = (__bf16)1.0f;

  f32x16 Oa0 = {}, Oa1 = {}, Sacc = {};

  // staging: each thread does 1 K 16B-slice + 1 V 16B-slice per tile
  const int srow = tid >> 3;                 // 0..63
  const int scb = (tid & 7) * 16;
  const int cbs = scb ^ ((srow & 7) << 4);   // pre-swizzled col byte (fixed/thread)
  const char* Kg = (const char*)(K + head) + srow * 128 + cbs;
  const char* Vg = (const char*)(Vt + head) + srow * 4096 + cbs;

  // prologue: stage tile 0 into buffer 0
  gload16(Kg, smem + w * 1024);
  gload16(Vg, smem + 8192 + w * 1024);
  Kg += 8192;   // next 64 K rows
  Vg += 128;    // next 64 kv columns
  __syncthreads();

  const int swz = (l31 & 7) << 4;

#define FLASH_TILE(T, CBUF, SBUF, DO_STAGE)                                    \
  {                                                                            \
    if (DO_STAGE) {                                                            \
      gload16(Kg, smem + (SBUF) + w * 1024);                                   \
      gload16(Vg, smem + (SBUF) + 8192 + w * 1024);                            \
      Kg += 8192; Vg += 128;                                                   \
    }                                                                          \
    const char* bK = smem + (CBUF);                                            \
    const char* bV = smem + (CBUF) + 8192;                                     \
    f32x16 s0 = {}, s1 = {};                                                   \
    __builtin_amdgcn_s_setprio(1);                                             \
    _Pragma("unroll")                                                          \
    for (int kk = 0; kk < 4; ++kk) {                                           \
      int col = (32 * kk + 16 * hi) ^ swz;                                     \
      bf16x8 k0 = *(const bf16x8*)(bK + l31 * 128 + col);                      \
      bf16x8 k1 = *(const bf16x8*)(bK + (l31 + 32) * 128 + col);               \
      s0 = mfma32(k0, qf[kk], s0);                                             \
      s1 = mfma32(k1, qf[kk], s1);                                             \
    }                                                                          \
    __builtin_amdgcn_s_setprio(0);                                             \
    float p0[16], p1[16];                                                      \
    _Pragma("unroll")                                                          \
    for (int i = 0; i < 16; ++i) {                                             \
      p0[i] = FEXP2(s0[i]);                                                    \
      p1[i] = FEXP2(s1[i]);                                                    \
    }                                                                          \
    if (anymask) {                                                             \
      int kv0 = (T) * 64;                                                      \
      _Pragma("unroll")                                                        \
      for (int r = 0; r < 16; ++r) {                                           \
        int crow = (r & 3) + 8 * (r >> 2) + 4 * hi;                            \
        if (mb[kv0 + crow]) p0[r] = 0.f;                                       \
        if (mb[kv0 + 32 + crow]) p1[r] = 0.f;                                  \
      }                                                                        \
    }                                                                          \
    uint32_t pw[4][4];                                                         \
    _Pragma("unroll")                                                          \
    for (int half = 0; half < 2; ++half) {                                     \
      const float* p = half ? p1 : p0;                                         \
      uint32_t alo0 = cvtpk(p[0], p[1]),  ahi0 = cvtpk(p[2], p[3]);            \
      uint32_t alo1 = cvtpk(p[4], p[5]),  ahi1 = cvtpk(p[6], p[7]);            \
      uint32_t alo2 = cvtpk(p[8], p[9]),  ahi2 = cvtpk(p[10], p[11]);          \
      uint32_t alo3 = cvtpk(p[12], p[13]), ahi3 = cvtpk(p[14], p[15]);         \
      auto r0 = __builtin_amdgcn_permlane32_swap(alo0, alo1, false, false);    \
      auto r1 = __builtin_amdgcn_permlane32_swap(ahi0, ahi1, false, false);    \
      auto r2 = __builtin_amdgcn_permlane32_swap(alo2, alo3, false, false);    \
      auto r3 = __builtin_amdgcn_permlane32_swap(ahi2, ahi3, false, false);    \
      pw[half * 2 + 0][0] = r0[0]; pw[half * 2 + 0][2] = r0[1];                \
      pw[half * 2 + 0][1] = r1[0]; pw[half * 2 + 0][3] = r1[1];                \
      pw[half * 2 + 1][0] = r2[0]; pw[half * 2 + 1][2] = r2[1];                \
      pw[half * 2 + 1][1] = r3[0]; pw[half * 2 + 1][3] = r3[1];                \
    }                                                                          \
    __builtin_amdgcn_s_setprio(1);                                             \
    _Pragma("unroll")                                                          \
    for (int c4 = 0; c4 < 4; ++c4) {                                           \
      union { uint32_t u[4]; bf16x8 v; } pf;                                   \
      pf.u[0] = pw[c4][0]; pf.u[1] = pw[c4][1];                                \
      pf.u[2] = pw[c4][2]; pf.u[3] = pw[c4][3];                                \
      int col = (32 * c4 + 16 * hi) ^ swz;                                     \
      bf16x8 v0 = *(const bf16x8*)(bV + l31 * 128 + col);                      \
      bf16x8 v1 = *(const bf16x8*)(bV + (l31 + 32) * 128 + col);               \
      Oa0 = mfma32(v0, pf.v, Oa0);                                             \
      Oa1 = mfma32(v1, pf.v, Oa1);                                             \
      Sacc = mfma32(vones, pf.v, Sacc);                                        \
    }                                                                          \
    __builtin_amdgcn_s_setprio(0);                                             \
    __syncthreads();                                                           \
  }

  for (int t = 0; t < N_ / 64; t += 2) {
    FLASH_TILE(t,     0,     16384, true)
    FLASH_TILE(t + 1, 16384, 0,     (t + 2 < N_ / 64))
  }
#undef FLASH_TILE

  // epilogue: O^T -> LDS transpose (per-wave region) -> coalesced global bf16
  float inv = 1.0f / Sacc[0];    // all rows of Sacc identical = sum_k P[q][k]
  char* tr = smem + w * 4608;    // [32 q][72 bf16] rows of 144B
#pragma unroll
  for (int db = 0; db < 2; ++db) {
    const f32x16& o = db ? Oa1 : Oa0;
#pragma unroll
    for (int a = 0; a < 4; ++a) {
      uint32_t lo = cvtpk(o[4 * a] * inv, o[4 * a + 1] * inv);
      uint32_t hi2 = cvtpk(o[4 * a + 2] * inv, o[4 * a + 3] * inv);
      *(uint2*)(tr + l31 * 144 + db * 64 + a * 16 + hi * 8) = make_uint2(lo, hi2);
    }
  }
  __asm__ volatile("" ::: "memory");
#pragma unroll
  for (int it = 0; it < 4; ++it) {
    uint4 v = *(const uint4*)(tr + l31 * 144 + it * 32 + hi * 16);
    int n = q0 + w * 32 + l31;
    *(uint4*)(O + (size_t)(b * 2048 + n) * 1024 + h * 64 + it * 16 + hi * 8) = v;
  }
}

// ---------------- host ----------------
extern "C" void kernel_launch(void* const* d_in, const int* in_sizes, int n_in,
                              void* d_out, int out_size, void* d_ws, size_t ws_size,
                              hipStream_t stream)
{
  (void)in_sizes; (void)n_in; (void)out_size; (void)ws_size;
  const float* x  = (const float*)d_in[0];
  const float* wq = (const float*)d_in[1];
  const float* bq = (const float*)d_in[2];
  const float* wk = (const float*)d_in[3];
  const float* bk = (const float*)d_in[4];
  const float* wv = (const float*)d_in[5];
  const float* bv = (const float*)d_in[6];
  const float* wo = (const float*)d_in[7];
  const float* bo = (const float*)d_in[8];
  const uint8_t* mask = (const uint8_t*)d_in[9];
  float* out = (float*)d_out;

  char* ws = (char*)d_ws;
  ushort* xb    = (ushort*)(ws + 0);              // 16 MB  (also attn-out bf16)
  ushort* Ab    = xb;
  ushort* wqkvb = (ushort*)(ws + 16777216);       // 6 MB packed [wq;wk;wv]
  ushort* wob   = (ushort*)(ws + 23068672);       // 2 MB
  ushort* Qb    = (ushort*)(ws + 25165824);       // 16 MB (B,H,N,Dh)
  ushort* Kb    = (ushort*)(ws + 41943040);       // 16 MB
  ushort* Vtb   = (ushort*)(ws + 58720256);       // 16 MB (B,H,Dh,N)
  float*  cost  = (float*)(ws + 75497472);        // 256 KB
  float*  sint  = (float*)(ws + 75759616);        // 256 KB

  prep<<<12544, 256, 0, stream>>>(x, wq, wk, wv, wo, xb, wqkvb, wob, cost, sint);

  gemm_qkv<<<dim3(M_ / 128, 24), 256, 0, stream>>>(xb, wqkvb, bq, bk, bv,
                                                   Qb, Kb, Vtb, cost, sint);

  flash_k<<<512, 512, 0, stream>>>(Qb, Kb, Vtb, mask, Ab);

  gemm_out<<<dim3(M_ / 128, 8), 256, 0, stream>>>(Ab, wob, bo, out);
}